// Round 4
// baseline (1234.012 us; speedup 1.0000x reference)
//
#include <hip/hip_runtime.h>
#include <hip/hip_bf16.h>

// SGConv (K=2) on MI355X.
// R1: dst-CSR + gather hops (no atomics on features).
// R2: coalesced matmul loads (FETCH 547->101 MB) — but latency-bound at
//     1.5 waves/SIMD (thread-per-row = only 1564 waves).
// R3: 4-way K-split matmul: thread=(row,j), float4-interleaved K partition,
//     shfl_xor reduce. 6250 waves, no LDS, no barriers.

#define TPB 256
#define SCAN_T 1024

// ---- histogram of incoming-edge counts at dst --------------------------
__global__ void k_hist(const int* __restrict__ dst, int* __restrict__ counts, int E) {
    int e = blockIdx.x * TPB + threadIdx.x;
    if (e < E) atomicAdd(&counts[dst[e]], 1);
}

// ---- single-block exclusive scan + cursor + dinv -----------------------
__global__ __launch_bounds__(SCAN_T) void k_scan(
    const int* __restrict__ counts, int* __restrict__ row_ptr,
    int* __restrict__ cursor, float* __restrict__ dinv, int N) {
    __shared__ int part[SCAN_T];
    int t = threadIdx.x;
    int chunk = (N + SCAN_T - 1) / SCAN_T;
    int beg = t * chunk;
    int end = min(beg + chunk, N);
    int s = 0;
    for (int i = beg; i < end; ++i) s += counts[i];
    part[t] = s;
    __syncthreads();
    for (int off = 1; off < SCAN_T; off <<= 1) {
        int v = (t >= off) ? part[t - off] : 0;
        __syncthreads();
        part[t] += v;
        __syncthreads();
    }
    int run = part[t] - s;          // exclusive prefix for this thread's chunk
    for (int i = beg; i < end; ++i) {
        int c = counts[i];
        row_ptr[i] = run;
        cursor[i]  = run;
        dinv[i]    = rsqrtf((float)(c + 1));   // +1 self-loop
        run += c;
    }
    if (t == SCAN_T - 1) row_ptr[N] = run;     // == E
}

// ---- scatter edges into CSR by dst -------------------------------------
__global__ void k_scatter(const int* __restrict__ src, const int* __restrict__ dst,
                          int* __restrict__ cursor, int* __restrict__ csr, int E) {
    int e = blockIdx.x * TPB + threadIdx.x;
    if (e < E) {
        int pos = atomicAdd(&cursor[dst[e]], 1);
        csr[pos] = src[e];
    }
}

// ---- z0 = dinv .* (x @ W^T) — 4-way K-split + shfl reduce --------------
// thread (row, j=lane&3): covers float4 positions {4m+j}, m=0..31.
// The 4 lanes of a row-group read 64B contiguous; W addr shared across groups.
__global__ __launch_bounds__(TPB) void k_matmul_xwt(
    const float* __restrict__ x, const float* __restrict__ W,
    const float* __restrict__ dinv, float* __restrict__ z, int N) {
    int t = blockIdx.x * TPB + threadIdx.x;
    int row = t >> 2;
    int j = t & 3;
    if (row >= N) return;
    float acc[40];
#pragma unroll
    for (int c = 0; c < 40; ++c) acc[c] = 0.f;
    const float4* xr = reinterpret_cast<const float4*>(x) + (size_t)row * 128;
    const float4* Wb = reinterpret_cast<const float4*>(W);
    for (int m = 0; m < 32; ++m) {
        float4 xv = xr[m * 4 + j];
#pragma unroll
        for (int c = 0; c < 40; ++c) {
            float4 wv = Wb[c * 128 + m * 4 + j];
            acc[c] = fmaf(xv.x, wv.x,
                     fmaf(xv.y, wv.y,
                     fmaf(xv.z, wv.z,
                     fmaf(xv.w, wv.w, acc[c]))));
        }
    }
    // butterfly-sum the 4 K-partials (lanes of one row-group)
#pragma unroll
    for (int c = 0; c < 40; ++c) {
        acc[c] += __shfl_xor(acc[c], 1);
        acc[c] += __shfl_xor(acc[c], 2);
    }
    if (j == 0) {
        float di = dinv[row];
        float4* zo = reinterpret_cast<float4*>(z + (size_t)row * 40);
#pragma unroll
        for (int c4 = 0; c4 < 10; ++c4)
            zo[c4] = make_float4(di * acc[c4*4], di * acc[c4*4+1],
                                 di * acc[c4*4+2], di * acc[c4*4+3]);
    }
}

// ---- gather hop: out[d] = dinv[d]^P * (z[d] + sum_{s in N(d)} z[s]) ----
// 10 threads per node, one float4 chunk each; register accumulation.
template <int P>
__global__ __launch_bounds__(TPB) void k_hop_csr(
    const int* __restrict__ csr, const int* __restrict__ row_ptr,
    const float* __restrict__ dinv, const float* __restrict__ zin,
    float* __restrict__ out, int N) {
    int t = blockIdx.x * TPB + threadIdx.x;
    int node = t / 10;
    int c4 = t - node * 10;
    if (node >= N) return;
    const float4* Z = reinterpret_cast<const float4*>(zin);
    float4 acc = Z[node * 10 + c4];            // self-loop term (z includes dinv)
    int beg = row_ptr[node];
    int end = row_ptr[node + 1];
    for (int j = beg; j < end; ++j) {
        int s = csr[j];                        // broadcast across the 10 lanes
        float4 v = Z[s * 10 + c4];
        acc.x += v.x; acc.y += v.y; acc.z += v.z; acc.w += v.w;
    }
    float dd = dinv[node];
    float sc = (P == 2) ? dd * dd : dd;
    float4 o = make_float4(sc*acc.x, sc*acc.y, sc*acc.z, sc*acc.w);
    reinterpret_cast<float4*>(out)[node * 10 + c4] = o;
}

// ---- log_softmax rows, in place on d_out, + bias -----------------------
__global__ __launch_bounds__(TPB) void k_logsoftmax(
    float* __restrict__ out, const float* __restrict__ b, int N) {
    int r = blockIdx.x * TPB + threadIdx.x;
    if (r >= N) return;
    float4* rowp = reinterpret_cast<float4*>(out + (size_t)r * 40);
    float v[40];
    float m = -1e30f;
#pragma unroll
    for (int c4 = 0; c4 < 10; ++c4) {
        float4 t = rowp[c4];
        v[c4*4+0] = t.x + b[c4*4+0];
        v[c4*4+1] = t.y + b[c4*4+1];
        v[c4*4+2] = t.z + b[c4*4+2];
        v[c4*4+3] = t.w + b[c4*4+3];
    }
#pragma unroll
    for (int c = 0; c < 40; ++c) m = fmaxf(m, v[c]);
    float sum = 0.f;
#pragma unroll
    for (int c = 0; c < 40; ++c) sum += __expf(v[c] - m);
    float lse = m + __logf(sum);
#pragma unroll
    for (int c4 = 0; c4 < 10; ++c4)
        rowp[c4] = make_float4(v[c4*4+0]-lse, v[c4*4+1]-lse, v[c4*4+2]-lse, v[c4*4+3]-lse);
}

extern "C" void kernel_launch(void* const* d_in, const int* in_sizes, int n_in,
                              void* d_out, int out_size, void* d_ws, size_t ws_size,
                              hipStream_t stream) {
    const float* x  = (const float*)d_in[0];
    const int*   ei = (const int*)d_in[1];
    const float* W  = (const float*)d_in[2];
    const float* b  = (const float*)d_in[3];
    float* out = (float*)d_out;

    const int N = in_sizes[0] / 512;     // 100000
    const int E = in_sizes[1] / 2;       // 3200000
    const int* src = ei;                 // edge_index[0]
    const int* dst = ei + E;             // edge_index[1]

    // workspace: z1 [N*40 f32] | csr [E i32] | counts [N] | row_ptr [N+1] | cursor [N] | dinv [N f32]
    float* z1      = (float*)d_ws;
    int*   csr     = (int*)(z1 + (size_t)N * 40);
    int*   counts  = csr + E;
    int*   row_ptr = counts + N;
    int*   cursor  = row_ptr + N + 1;
    float* dinv    = (float*)(cursor + N);
    float* z0      = out;                // stage z0 in d_out, overwritten by hop2

    hipMemsetAsync(counts, 0, (size_t)N * sizeof(int), stream);

    int gN = (N + TPB - 1) / TPB;
    int gE = (E + TPB - 1) / TPB;
    int gM = (N * 4 + TPB - 1) / TPB;
    int gH = (N * 10 + TPB - 1) / TPB;

    k_hist<<<gE, TPB, 0, stream>>>(dst, counts, E);
    k_scan<<<1, SCAN_T, 0, stream>>>(counts, row_ptr, cursor, dinv, N);
    k_scatter<<<gE, TPB, 0, stream>>>(src, dst, cursor, csr, E);

    k_matmul_xwt<<<gM, TPB, 0, stream>>>(x, W, dinv, z0, N);

    k_hop_csr<2><<<gH, TPB, 0, stream>>>(csr, row_ptr, dinv, z0, z1, N);   // hop 1
    k_hop_csr<1><<<gH, TPB, 0, stream>>>(csr, row_ptr, dinv, z1, out, N);  // hop 2

    k_logsoftmax<<<gN, TPB, 0, stream>>>(out, b, N);
}

// Round 5
// 960.625 us; speedup vs baseline: 1.2846x; 1.2846x over previous
//
#include <hip/hip_runtime.h>
#include <hip/hip_bf16.h>

// SGConv (K=2) on MI355X.
// R1: dst-CSR + gather hops (no atomics on features).
// R2: coalesced matmul loads (FETCH 547->101 MB).
// R3 FAILED: 4-way K-split broke W broadcast -> per-lane VMEM storm (410us).
//    Root cause of the ~310us plateau: scalar matmul issues ~1300 VMEM W-loads
//    per output row. Fix: MFMA.
// R4: bf16 MFMA matmul (16x16x32), W pre-converted to [48][512] bf16 table.

#define TPB 256
#define SCAN_T 1024

typedef __attribute__((ext_vector_type(8))) short short8v;   // bf16x8, 4 VGPRs
typedef __attribute__((ext_vector_type(4))) float f32x4;

__device__ inline short f2bf(float f) {            // RNE f32->bf16 (finite data)
    unsigned u = __float_as_uint(f);
    unsigned r = (u + 0x7fffu + ((u >> 16) & 1u)) >> 16;
    return (short)r;
}

// ---- histogram of incoming-edge counts at dst --------------------------
__global__ void k_hist(const int* __restrict__ dst, int* __restrict__ counts, int E) {
    int e = blockIdx.x * TPB + threadIdx.x;
    if (e < E) atomicAdd(&counts[dst[e]], 1);
}

// ---- single-block exclusive scan + cursor + dinv -----------------------
__global__ __launch_bounds__(SCAN_T) void k_scan(
    const int* __restrict__ counts, int* __restrict__ row_ptr,
    int* __restrict__ cursor, float* __restrict__ dinv, int N) {
    __shared__ int part[SCAN_T];
    int t = threadIdx.x;
    int chunk = (N + SCAN_T - 1) / SCAN_T;
    int beg = t * chunk;
    int end = min(beg + chunk, N);
    int s = 0;
    for (int i = beg; i < end; ++i) s += counts[i];
    part[t] = s;
    __syncthreads();
    for (int off = 1; off < SCAN_T; off <<= 1) {
        int v = (t >= off) ? part[t - off] : 0;
        __syncthreads();
        part[t] += v;
        __syncthreads();
    }
    int run = part[t] - s;          // exclusive prefix for this thread's chunk
    for (int i = beg; i < end; ++i) {
        int c = counts[i];
        row_ptr[i] = run;
        cursor[i]  = run;
        dinv[i]    = rsqrtf((float)(c + 1));   // +1 self-loop
        run += c;
    }
    if (t == SCAN_T - 1) row_ptr[N] = run;     // == E
}

// ---- scatter edges into CSR by dst -------------------------------------
__global__ void k_scatter(const int* __restrict__ src, const int* __restrict__ dst,
                          int* __restrict__ cursor, int* __restrict__ csr, int E) {
    int e = blockIdx.x * TPB + threadIdx.x;
    if (e < E) {
        int pos = atomicAdd(&cursor[dst[e]], 1);
        csr[pos] = src[e];
    }
}

// ---- W (40x512 f32) -> Wb (48x512 bf16, rows 40..47 zero) --------------
__global__ void k_wconv(const float* __restrict__ W, short* __restrict__ Wb) {
    int idx = blockIdx.x * TPB + threadIdx.x;    // 0..24575
    int c = idx >> 9, k = idx & 511;
    float v = (c < 40) ? W[c * 512 + k] : 0.f;
    Wb[idx] = f2bf(v);
}

// ---- z0 = dinv .* (x @ W^T) via MFMA bf16 ------------------------------
// Block 256 = 4 waves; wave computes 16 rows x 48 cols (3 c-tiles), K=512.
// A frag: row=lane&15, k=(lane>>4)*8+j (16B f32x8 -> bf16x8, per m89/m91).
// B frag: col=lane&15, same k runs, from Wb [48][512] bf16.
// D frag: col=lane&15, row=(lane>>4)*4+reg.
__global__ __launch_bounds__(TPB) void k_matmul_mfma(
    const float* __restrict__ x, const short* __restrict__ Wb,
    const float* __restrict__ dinv, float* __restrict__ z, int N) {
    int wid  = threadIdx.x >> 6;
    int lane = threadIdx.x & 63;
    int rbase = blockIdx.x * 64 + wid * 16;
    if (rbase >= N) return;                       // wave-uniform, no barriers
    int arow   = rbase + (lane & 15);
    int aclamp = min(arow, N - 1);
    int koff   = (lane >> 4) * 8;
    const float* xrow = x + (size_t)aclamp * 512 + koff;
    const short* wb   = Wb + (lane & 15) * 512 + koff;

    f32x4 acc0 = {0.f,0.f,0.f,0.f}, acc1 = {0.f,0.f,0.f,0.f}, acc2 = {0.f,0.f,0.f,0.f};
    for (int ks = 0; ks < 16; ++ks) {
        int k0 = ks * 32;
        float4 f0 = *reinterpret_cast<const float4*>(xrow + k0);
        float4 f1 = *reinterpret_cast<const float4*>(xrow + k0 + 4);
        short8v a;
        a[0] = f2bf(f0.x); a[1] = f2bf(f0.y); a[2] = f2bf(f0.z); a[3] = f2bf(f0.w);
        a[4] = f2bf(f1.x); a[5] = f2bf(f1.y); a[6] = f2bf(f1.z); a[7] = f2bf(f1.w);
        short8v b0 = *reinterpret_cast<const short8v*>(wb + k0);
        short8v b1 = *reinterpret_cast<const short8v*>(wb + 16 * 512 + k0);
        short8v b2 = *reinterpret_cast<const short8v*>(wb + 32 * 512 + k0);
        acc0 = __builtin_amdgcn_mfma_f32_16x16x32_bf16(a, b0, acc0, 0, 0, 0);
        acc1 = __builtin_amdgcn_mfma_f32_16x16x32_bf16(a, b1, acc1, 0, 0, 0);
        acc2 = __builtin_amdgcn_mfma_f32_16x16x32_bf16(a, b2, acc2, 0, 0, 0);
    }
    int col = lane & 15;
    int rw  = rbase + (lane >> 4) * 4;
#pragma unroll
    for (int reg = 0; reg < 4; ++reg) {
        int r = rw + reg;
        if (r < N) {
            float di = dinv[r];
            z[(size_t)r * 40 + col]      = di * acc0[reg];
            z[(size_t)r * 40 + 16 + col] = di * acc1[reg];
            if (col < 8)
                z[(size_t)r * 40 + 32 + col] = di * acc2[reg];
        }
    }
}

// ---- gather hop: out[d] = dinv[d]^P * (z[d] + sum_{s in N(d)} z[s]) ----
template <int P>
__global__ __launch_bounds__(TPB) void k_hop_csr(
    const int* __restrict__ csr, const int* __restrict__ row_ptr,
    const float* __restrict__ dinv, const float* __restrict__ zin,
    float* __restrict__ out, int N) {
    int t = blockIdx.x * TPB + threadIdx.x;
    int node = t / 10;
    int c4 = t - node * 10;
    if (node >= N) return;
    const float4* Z = reinterpret_cast<const float4*>(zin);
    float4 acc = Z[node * 10 + c4];            // self-loop term (z includes dinv)
    int beg = row_ptr[node];
    int end = row_ptr[node + 1];
    for (int j = beg; j < end; ++j) {
        int s = csr[j];                        // broadcast across the 10 lanes
        float4 v = Z[s * 10 + c4];
        acc.x += v.x; acc.y += v.y; acc.z += v.z; acc.w += v.w;
    }
    float dd = dinv[node];
    float sc = (P == 2) ? dd * dd : dd;
    reinterpret_cast<float4*>(out)[node * 10 + c4] =
        make_float4(sc*acc.x, sc*acc.y, sc*acc.z, sc*acc.w);
}

// ---- log_softmax rows, in place on d_out, + bias -----------------------
__global__ __launch_bounds__(TPB) void k_logsoftmax(
    float* __restrict__ out, const float* __restrict__ b, int N) {
    int r = blockIdx.x * TPB + threadIdx.x;
    if (r >= N) return;
    float4* rowp = reinterpret_cast<float4*>(out + (size_t)r * 40);
    float v[40];
    float m = -1e30f;
#pragma unroll
    for (int c4 = 0; c4 < 10; ++c4) {
        float4 t = rowp[c4];
        v[c4*4+0] = t.x + b[c4*4+0];
        v[c4*4+1] = t.y + b[c4*4+1];
        v[c4*4+2] = t.z + b[c4*4+2];
        v[c4*4+3] = t.w + b[c4*4+3];
    }
#pragma unroll
    for (int c = 0; c < 40; ++c) m = fmaxf(m, v[c]);
    float sum = 0.f;
#pragma unroll
    for (int c = 0; c < 40; ++c) sum += __expf(v[c] - m);
    float lse = m + __logf(sum);
#pragma unroll
    for (int c4 = 0; c4 < 10; ++c4)
        rowp[c4] = make_float4(v[c4*4+0]-lse, v[c4*4+1]-lse, v[c4*4+2]-lse, v[c4*4+3]-lse);
}

extern "C" void kernel_launch(void* const* d_in, const int* in_sizes, int n_in,
                              void* d_out, int out_size, void* d_ws, size_t ws_size,
                              hipStream_t stream) {
    const float* x  = (const float*)d_in[0];
    const int*   ei = (const int*)d_in[1];
    const float* W  = (const float*)d_in[2];
    const float* b  = (const float*)d_in[3];
    float* out = (float*)d_out;

    const int N = in_sizes[0] / 512;     // 100000
    const int E = in_sizes[1] / 2;       // 3200000
    const int* src = ei;                 // edge_index[0]
    const int* dst = ei + E;             // edge_index[1]

    // workspace: z1 [N*40 f32] | csr [E i32] | counts [N] | row_ptr [N+1] | cursor [N] | dinv [N f32]
    float* z1      = (float*)d_ws;
    int*   csr     = (int*)(z1 + (size_t)N * 40);
    int*   counts  = csr + E;
    int*   row_ptr = counts + N;
    int*   cursor  = row_ptr + N + 1;
    float* dinv    = (float*)(cursor + N);
    float* z0      = out;                // stage z0 in d_out, overwritten by hop2
    // Wb (48x512 bf16 = 48KB) aliases the TAIL of z1: written by k_wconv and
    // read by k_matmul_mfma (both before hop1, which overwrites z1 entirely).
    short* Wb      = (short*)(z1 + (size_t)N * 40) - 48 * 512;

    hipMemsetAsync(counts, 0, (size_t)N * sizeof(int), stream);

    int gN = (N + TPB - 1) / TPB;
    int gE = (E + TPB - 1) / TPB;
    int gM = (N + 63) / 64;
    int gH = (N * 10 + TPB - 1) / TPB;

    k_wconv<<<(48 * 512) / TPB, TPB, 0, stream>>>(W, Wb);
    k_hist<<<gE, TPB, 0, stream>>>(dst, counts, E);
    k_scan<<<1, SCAN_T, 0, stream>>>(counts, row_ptr, cursor, dinv, N);
    k_scatter<<<gE, TPB, 0, stream>>>(src, dst, cursor, csr, E);

    k_matmul_mfma<<<gM, TPB, 0, stream>>>(x, Wb, dinv, z0, N);

    k_hop_csr<2><<<gH, TPB, 0, stream>>>(csr, row_ptr, dinv, z0, z1, N);   // hop 1
    k_hop_csr<1><<<gH, TPB, 0, stream>>>(csr, row_ptr, dinv, z1, out, N);  // hop 2

    k_logsoftmax<<<gN, TPB, 0, stream>>>(out, b, N);
}